// Round 1
// baseline (5898.024 us; speedup 1.0000x reference)
//
#include <hip/hip_runtime.h>
#include <math.h>

#define H_   8
#define E_   512
#define DK   64
#define BB   16
#define T1C  512
#define T2C  512
#define NPOS 1023

// C[m,n] = sum_k A[m,k] * W[n,k] + bias[n]   (A: MxE, W: ExE row-major -> NT gemm)
__global__ __launch_bounds__(256) void gemm_nt(
    const float* __restrict__ A, const float* __restrict__ W,
    const float* __restrict__ bias, float* __restrict__ C, int M)
{
    __shared__ float As[16][65];
    __shared__ float Bs[16][65];
    const int tid = threadIdx.x;
    const int tx = tid & 15, ty = tid >> 4;
    const int n0 = blockIdx.x * 64;
    const int m0 = blockIdx.y * 64;
    const int lr = tid >> 2;          // 0..63 row within tile
    const int lc = (tid & 3) << 2;    // 0,4,8,12 col within k-chunk
    float acc[4][4] = {{0.f,0.f,0.f,0.f},{0.f,0.f,0.f,0.f},{0.f,0.f,0.f,0.f},{0.f,0.f,0.f,0.f}};

    for (int k0 = 0; k0 < E_; k0 += 16) {
        const int am = m0 + lr;
        float4 av = make_float4(0.f, 0.f, 0.f, 0.f);
        if (am < M) av = *(const float4*)(A + (size_t)am * E_ + k0 + lc);
        As[lc + 0][lr] = av.x; As[lc + 1][lr] = av.y;
        As[lc + 2][lr] = av.z; As[lc + 3][lr] = av.w;
        const float4 wv = *(const float4*)(W + (size_t)(n0 + lr) * E_ + k0 + lc);
        Bs[lc + 0][lr] = wv.x; Bs[lc + 1][lr] = wv.y;
        Bs[lc + 2][lr] = wv.z; Bs[lc + 3][lr] = wv.w;
        __syncthreads();
        #pragma unroll
        for (int kk = 0; kk < 16; ++kk) {
            float a[4], b[4];
            #pragma unroll
            for (int ii = 0; ii < 4; ++ii) a[ii] = As[kk][ty * 4 + ii];
            #pragma unroll
            for (int jj = 0; jj < 4; ++jj) b[jj] = Bs[kk][tx * 4 + jj];
            #pragma unroll
            for (int ii = 0; ii < 4; ++ii)
                #pragma unroll
                for (int jj = 0; jj < 4; ++jj)
                    acc[ii][jj] += a[ii] * b[jj];
        }
        __syncthreads();
    }

    #pragma unroll
    for (int ii = 0; ii < 4; ++ii) {
        const int m = m0 + ty * 4 + ii;
        if (m < M) {
            #pragma unroll
            for (int jj = 0; jj < 4; ++jj) {
                const int n = n0 + tx * 4 + jj;
                float r = acc[ii][jj];
                if (bias) r += bias[n];
                C[(size_t)m * E_ + n] = r;
            }
        }
    }
}

// One block per (b, h, i): full row of scores -> masked softmax -> attn @ V
__global__ __launch_bounds__(256) void attn_kernel(
    const float* __restrict__ Q,   // (B,T1,H,DK)
    const float* __restrict__ K,   // (B,T2,H,DK)
    const float* __restrict__ V,   // (B,T2,H,DK)
    const float* __restrict__ P,   // (B,NPOS,H,DK)
    const float* __restrict__ pbu, // (H,DK)
    const float* __restrict__ pbv, // (H,DK)
    const unsigned char* __restrict__ mask,        // (B,T2) bool
    const unsigned char* __restrict__ chunk_mask,  // (T1,T1) bool
    float* __restrict__ CTX)       // (B,T1,H,DK)  (may alias Q: per-slice r-then-w)
{
    const int i = blockIdx.x, h = blockIdx.y, b = blockIdx.z;
    const int tid = threadIdx.x;

    __shared__ float qu[DK], qv[DK];
    __shared__ float s[T2C];
    __shared__ float wred[4];
    __shared__ float red2[256];

    if (tid < DK) {
        const float qd = Q[(((size_t)b * T1C + i) * H_ + h) * DK + tid];
        qu[tid] = qd + pbu[h * DK + tid];
        qv[tid] = qd + pbv[h * DK + tid];
    }
    __syncthreads();

    const float scale = 0.125f;  // 1/sqrt(64)
    const float NEGF = -3.402823466e38f;

    float sc[2];
    bool msk[2];
    #pragma unroll
    for (int t = 0; t < 2; ++t) {
        const int j = tid + t * 256;
        msk[t] = (chunk_mask[(size_t)i * T1C + j] | mask[(size_t)b * T2C + j]) != 0;
        const float* kr = K + (((size_t)b * T2C + j) * H_ + h) * DK;
        const int n = j - i + (T1C - 1);
        const float* pr = P + (((size_t)b * NPOS + n) * H_ + h) * DK;
        float acc1 = 0.f, acc2 = 0.f;
        #pragma unroll
        for (int d = 0; d < DK; d += 4) {
            const float4 kv4 = *(const float4*)(kr + d);
            acc1 += qu[d] * kv4.x + qu[d + 1] * kv4.y + qu[d + 2] * kv4.z + qu[d + 3] * kv4.w;
            const float4 pv4 = *(const float4*)(pr + d);
            acc2 += qv[d] * pv4.x + qv[d + 1] * pv4.y + qv[d + 2] * pv4.z + qv[d + 3] * pv4.w;
        }
        float v = (acc1 + acc2) * scale;
        sc[t] = msk[t] ? NEGF : v;
    }

    // block max
    float r = fmaxf(sc[0], sc[1]);
    #pragma unroll
    for (int off = 32; off; off >>= 1) r = fmaxf(r, __shfl_down(r, off));
    if ((tid & 63) == 0) wred[tid >> 6] = r;
    __syncthreads();
    const float mx = fmaxf(fmaxf(wred[0], wred[1]), fmaxf(wred[2], wred[3]));
    __syncthreads();

    // exp + block sum (reference sums exp over ALL j, zeroes masked after)
    const float e0 = expf(sc[0] - mx);
    const float e1 = expf(sc[1] - mx);
    r = e0 + e1;
    #pragma unroll
    for (int off = 32; off; off >>= 1) r += __shfl_down(r, off);
    if ((tid & 63) == 0) wred[tid >> 6] = r;
    __syncthreads();
    const float denom = (wred[0] + wred[1]) + (wred[2] + wred[3]);
    const float inv = 1.0f / denom;

    s[tid]       = msk[0] ? 0.f : e0;
    s[tid + 256] = msk[1] ? 0.f : e1;
    __syncthreads();

    // ctx[d] = inv * sum_j s[j] * V[b,j,h,d]
    const int d = tid & 63, g = tid >> 6;
    float accv = 0.f;
    for (int j = g; j < T2C; j += 4) {
        accv += s[j] * V[(((size_t)b * T2C + j) * H_ + h) * DK + d];
    }
    red2[tid] = accv;
    __syncthreads();
    if (g == 0) {
        const float tot = (red2[d] + red2[64 + d]) + (red2[128 + d] + red2[192 + d]);
        CTX[(((size_t)b * T1C + i) * H_ + h) * DK + d] = tot * inv;
    }
}

extern "C" void kernel_launch(void* const* d_in, const int* in_sizes, int n_in,
                              void* d_out, int out_size, void* d_ws, size_t ws_size,
                              hipStream_t stream) {
    const float* query   = (const float*)d_in[0];
    const float* key     = (const float*)d_in[1];
    const float* value   = (const float*)d_in[2];
    const float* pos_enc = (const float*)d_in[3];
    const unsigned char* mask       = (const unsigned char*)d_in[4];
    const unsigned char* chunk_mask = (const unsigned char*)d_in[5];
    const float* Wq  = (const float*)d_in[6];
    const float* bq  = (const float*)d_in[7];
    const float* Wk  = (const float*)d_in[8];
    const float* bk  = (const float*)d_in[9];
    const float* Wv  = (const float*)d_in[10];
    const float* bv  = (const float*)d_in[11];
    const float* Wpos = (const float*)d_in[12];
    const float* Wo   = (const float*)d_in[13];
    const float* bo   = (const float*)d_in[14];
    const float* pbu  = (const float*)d_in[15];
    const float* pbv  = (const float*)d_in[16];
    float* out = (float*)d_out;

    // workspace layout (floats)
    float* ws = (float*)d_ws;
    const size_t SZ_QKV = (size_t)BB * T1C * E_;   // 4,194,304
    float* Qb = ws;                    // also CTX (safe per-slice alias)
    float* Kb = ws + SZ_QKV;
    float* Vb = ws + 2 * SZ_QKV;
    float* Pb = ws + 3 * SZ_QKV;       // 16*1023*512 = 8,380,416 floats

    const int Mqkv = BB * T1C;         // 8192
    const int Mpos = BB * NPOS;        // 16368

    dim3 gblk(256);
    dim3 ggrid(E_ / 64, (Mqkv + 63) / 64);
    dim3 pgrid(E_ / 64, (Mpos + 63) / 64);

    gemm_nt<<<ggrid, gblk, 0, stream>>>(query,   Wq,   bq,      Qb, Mqkv);
    gemm_nt<<<ggrid, gblk, 0, stream>>>(key,     Wk,   bk,      Kb, Mqkv);
    gemm_nt<<<ggrid, gblk, 0, stream>>>(value,   Wv,   bv,      Vb, Mqkv);
    gemm_nt<<<pgrid, gblk, 0, stream>>>(pos_enc, Wpos, nullptr, Pb, Mpos);

    dim3 agrid(T1C, H_, BB);
    attn_kernel<<<agrid, dim3(256), 0, stream>>>(Qb, Kb, Vb, Pb, pbu, pbv,
                                                 mask, chunk_mask, Qb /*CTX*/);

    gemm_nt<<<ggrid, gblk, 0, stream>>>(Qb, Wo, bo, out, Mqkv);
}

// Round 2
// 1029.231 us; speedup vs baseline: 5.7305x; 5.7305x over previous
//
#include <hip/hip_runtime.h>
#include <math.h>

#define H_   8
#define E_   512
#define DK   64
#define BB   16
#define T1C  512
#define T2C  512
#define NPOS 1023

__device__ __forceinline__ unsigned short f2bf(float x) {
    unsigned int u = __float_as_uint(x);
    u = (u + 0x7FFFu + ((u >> 16) & 1u)) >> 16;   // RNE
    return (unsigned short)u;
}
__device__ __forceinline__ float bf2f(unsigned short h) {
    return __uint_as_float(((unsigned int)h) << 16);
}

// C = A @ W^T + bias. mode 0: C (M,512) row-major. mode 1: head-major (B,H,512,64).
// mode 2: head-major (B,H,1023,64).
__global__ __launch_bounds__(256) void gemm_nt(
    const float* __restrict__ A, const float* __restrict__ W,
    const float* __restrict__ bias, float* __restrict__ C, int M, int mode)
{
    __shared__ float As[16][65];
    __shared__ float Bs[16][65];
    const int tid = threadIdx.x;
    const int tx = tid & 15, ty = tid >> 4;
    const int n0 = blockIdx.x * 64;
    const int m0 = blockIdx.y * 64;
    const int lr = tid >> 2;
    const int lc = (tid & 3) << 2;
    float acc[4][4] = {{0.f,0.f,0.f,0.f},{0.f,0.f,0.f,0.f},{0.f,0.f,0.f,0.f},{0.f,0.f,0.f,0.f}};

    for (int k0 = 0; k0 < E_; k0 += 16) {
        const int am = m0 + lr;
        float4 av = make_float4(0.f, 0.f, 0.f, 0.f);
        if (am < M) av = *(const float4*)(A + (size_t)am * E_ + k0 + lc);
        As[lc + 0][lr] = av.x; As[lc + 1][lr] = av.y;
        As[lc + 2][lr] = av.z; As[lc + 3][lr] = av.w;
        const float4 wv = *(const float4*)(W + (size_t)(n0 + lr) * E_ + k0 + lc);
        Bs[lc + 0][lr] = wv.x; Bs[lc + 1][lr] = wv.y;
        Bs[lc + 2][lr] = wv.z; Bs[lc + 3][lr] = wv.w;
        __syncthreads();
        #pragma unroll
        for (int kk = 0; kk < 16; ++kk) {
            float a[4], b[4];
            #pragma unroll
            for (int ii = 0; ii < 4; ++ii) a[ii] = As[kk][ty * 4 + ii];
            #pragma unroll
            for (int jj = 0; jj < 4; ++jj) b[jj] = Bs[kk][tx * 4 + jj];
            #pragma unroll
            for (int ii = 0; ii < 4; ++ii)
                #pragma unroll
                for (int jj = 0; jj < 4; ++jj)
                    acc[ii][jj] += a[ii] * b[jj];
        }
        __syncthreads();
    }

    #pragma unroll
    for (int ii = 0; ii < 4; ++ii) {
        const int m = m0 + ty * 4 + ii;
        if (m >= M) continue;
        #pragma unroll
        for (int jj = 0; jj < 4; ++jj) {
            const int n = n0 + tx * 4 + jj;
            float r = acc[ii][jj];
            if (bias) r += bias[n];
            if (mode == 0) {
                C[(size_t)m * E_ + n] = r;
            } else {
                const int hh = n >> 6, dk = n & 63;
                if (mode == 1) {
                    const int bI = m >> 9, t = m & 511;
                    C[(((size_t)bI * H_ + hh) * T2C + t) * DK + dk] = r;
                } else {
                    const int bI = m / NPOS, t = m - bI * NPOS;
                    C[(((size_t)bI * H_ + hh) * NPOS + t) * DK + dk] = r;
                }
            }
        }
    }
}

// Tiled online-softmax attention with rel-shift.
// Block = (i-tile of 64, h, b); 256 threads; 4x4 microtiles.
// LDS: QT 16K + slotA 16K (KT -> BDW(bf16) -> Ws) + PTb 16K (bf16) = 48.25K
__global__ __launch_bounds__(256) void attn_tiled(
    const float* __restrict__ Qo,   // (B,T1,E), col n = h*64+dk  ("q + pbu" added on load)
    const float* __restrict__ Kh,   // (B,H,T2,DK)
    const float* __restrict__ Vh,   // (B,H,T2,DK)
    const float* __restrict__ Ph,   // (B,H,NPOS,DK)
    const float* __restrict__ pbu, const float* __restrict__ pbv,
    const unsigned char* __restrict__ bmask,   // (B,T2)
    const unsigned char* __restrict__ cmask,   // (T1,T1)
    float* __restrict__ CTX)        // (B,T1,E) — aliases Qo (same slice r-then-w per block)
{
    __shared__ float QT[64 * 64];             // [d][r] = q+u
    __shared__ float slotA[64 * 64];          // KT [d][c] | BDW bf16 64x128 | Ws [c][r]
    __shared__ unsigned short PTb[64 * 128];  // [d][nw] bf16
    __shared__ float dpb[DK];                 // pbv - pbu

    const int tid = threadIdx.x;
    const int tx = tid & 15, ty = tid >> 4;
    const int it = blockIdx.x, h = blockIdx.y, b = blockIdx.z;
    const int i0 = it * 64;
    const int bh = b * H_ + h;

    // Q tile (+pbu), transposed into QT[d][r]
    #pragma unroll
    for (int rep = 0; rep < 4; ++rep) {
        const int flat = rep * 1024 + tid * 4;
        const int r = flat >> 6, d = flat & 63;
        const float4 q = *(const float4*)(Qo + ((size_t)(b * T1C + i0 + r)) * E_ + h * DK + d);
        const float4 u4 = *(const float4*)(pbu + h * DK + d);
        QT[(d + 0) * 64 + r] = q.x + u4.x;
        QT[(d + 1) * 64 + r] = q.y + u4.y;
        QT[(d + 2) * 64 + r] = q.z + u4.z;
        QT[(d + 3) * 64 + r] = q.w + u4.w;
    }
    if (tid < DK) dpb[tid] = pbv[h * DK + tid] - pbu[h * DK + tid];

    float m_run[4], l_run[4], o[4][4];
    #pragma unroll
    for (int ii = 0; ii < 4; ++ii) {
        m_run[ii] = -__builtin_inff(); l_run[ii] = 0.f;
        #pragma unroll
        for (int dd = 0; dd < 4; ++dd) o[ii][dd] = 0.f;
    }

    for (int jt = 0; jt < 8; ++jt) {
        const int j0 = jt * 64;
        const int nbase = j0 - i0 + 448;   // window start; in [0, 896]
        __syncthreads();
        // K tile -> slotA[d][c]
        #pragma unroll
        for (int rep = 0; rep < 4; ++rep) {
            const int flat = rep * 1024 + tid * 4;
            const int c = flat >> 6, d = flat & 63;
            const float4 k = *(const float4*)(Kh + ((size_t)bh * T2C + j0 + c) * DK + d);
            slotA[(d + 0) * 64 + c] = k.x;
            slotA[(d + 1) * 64 + c] = k.y;
            slotA[(d + 2) * 64 + c] = k.z;
            slotA[(d + 3) * 64 + c] = k.w;
        }
        // P window (127 rows + 1 pad) -> PTb[d][nw] bf16
        #pragma unroll
        for (int rep = 0; rep < 8; ++rep) {
            const int flat = rep * 1024 + tid * 4;
            const int nw = flat >> 6, d = flat & 63;
            int n = nbase + nw; n = n > (NPOS - 1) ? (NPOS - 1) : n;  // pad row clamp
            const float4 p = *(const float4*)(Ph + ((size_t)bh * NPOS + n) * DK + d);
            PTb[(d + 0) * 128 + nw] = f2bf(p.x);
            PTb[(d + 1) * 128 + nw] = f2bf(p.y);
            PTb[(d + 2) * 128 + nw] = f2bf(p.z);
            PTb[(d + 3) * 128 + nw] = f2bf(p.w);
        }
        __syncthreads();

        // AC (16 out) + windowed BD GEMM (32 out) + (v-u)·p accumulator, fused d-loop
        float ac[4][4] = {}, bd[4][8] = {}, vp[8] = {};
        #pragma unroll 2
        for (int d = 0; d < DK; ++d) {
            float a[4], k[4], p[8];
            *(float4*)a = *(const float4*)&QT[d * 64 + ty * 4];
            *(float4*)k = *(const float4*)&slotA[d * 64 + tx * 4];
            union { float4 f; unsigned short s[8]; } pr;
            pr.f = *(const float4*)&PTb[d * 128 + tx * 8];
            #pragma unroll
            for (int j = 0; j < 8; ++j) p[j] = bf2f(pr.s[j]);
            const float db = dpb[d];
            #pragma unroll
            for (int ii = 0; ii < 4; ++ii)
                #pragma unroll
                for (int jj = 0; jj < 4; ++jj)
                    ac[ii][jj] += a[ii] * k[jj];
            #pragma unroll
            for (int ii = 0; ii < 4; ++ii)
                #pragma unroll
                for (int jj = 0; jj < 8; ++jj)
                    bd[ii][jj] += a[ii] * p[jj];
            #pragma unroll
            for (int jj = 0; jj < 8; ++jj) vp[jj] += db * p[jj];
        }
        __syncthreads();

        // BDW (incl. (v-u)·p term) -> slotA as bf16 64x128
        unsigned short* BDW = (unsigned short*)slotA;
        #pragma unroll
        for (int ii = 0; ii < 4; ++ii) {
            union { float4 f; unsigned short s[8]; } pk;
            #pragma unroll
            for (int jj = 0; jj < 8; ++jj) pk.s[jj] = f2bf(bd[ii][jj] + vp[jj]);
            *(float4*)&BDW[(ty * 4 + ii) * 128 + tx * 8] = pk.f;
        }
        __syncthreads();

        // gather shifted BD, mask, online softmax update
        float w[4][4];
        #pragma unroll
        for (int ii = 0; ii < 4; ++ii) {
            const int r = ty * 4 + ii;
            float s4[4]; unsigned mk4 = 0;
            #pragma unroll
            for (int jj = 0; jj < 4; ++jj) {
                const int c = tx * 4 + jj;
                float sv = (ac[ii][jj] + bf2f(BDW[r * 128 + (c - r + 63)])) * 0.125f;
                const bool mk = (cmask[(size_t)(i0 + r) * T1C + j0 + c] |
                                 bmask[(size_t)b * T2C + j0 + c]) != 0;
                if (mk) { sv = -3.402823466e38f; mk4 |= (1u << jj); }
                s4[jj] = sv;
            }
            float tmax = fmaxf(fmaxf(s4[0], s4[1]), fmaxf(s4[2], s4[3]));
            #pragma unroll
            for (int d = 1; d < 16; d <<= 1) tmax = fmaxf(tmax, __shfl_xor(tmax, d));
            const float mnew = fmaxf(m_run[ii], tmax);
            const float alpha = __expf(m_run[ii] - mnew);
            float rsum = 0.f;
            #pragma unroll
            for (int jj = 0; jj < 4; ++jj) {
                const float e = __expf(s4[jj] - mnew);
                rsum += e;                         // denom over all j (ref semantics)
                w[ii][jj] = ((mk4 >> jj) & 1u) ? 0.f : e;  // zero masked for PV
            }
            #pragma unroll
            for (int d = 1; d < 16; d <<= 1) rsum += __shfl_xor(rsum, d);
            l_run[ii] = l_run[ii] * alpha + rsum;
            m_run[ii] = mnew;
            #pragma unroll
            for (int dd = 0; dd < 4; ++dd) o[ii][dd] *= alpha;
        }
        __syncthreads();
        // weights -> slotA as Ws[c][r]
        #pragma unroll
        for (int ii = 0; ii < 4; ++ii)
            #pragma unroll
            for (int jj = 0; jj < 4; ++jj)
                slotA[(tx * 4 + jj) * 64 + ty * 4 + ii] = w[ii][jj];
        __syncthreads();
        // PV: V from global (L2-hot), weights from LDS
        #pragma unroll 4
        for (int c = 0; c < 64; ++c) {
            float w4[4], v4[4];
            *(float4*)w4 = *(const float4*)&slotA[c * 64 + ty * 4];
            *(float4*)v4 = *(const float4*)(Vh + ((size_t)bh * T2C + j0 + c) * DK + tx * 4);
            #pragma unroll
            for (int ii = 0; ii < 4; ++ii)
                #pragma unroll
                for (int dd = 0; dd < 4; ++dd)
                    o[ii][dd] += w4[ii] * v4[dd];
        }
    }

    #pragma unroll
    for (int ii = 0; ii < 4; ++ii) {
        const float invl = 1.0f / l_run[ii];
        float4 res;
        res.x = o[ii][0] * invl; res.y = o[ii][1] * invl;
        res.z = o[ii][2] * invl; res.w = o[ii][3] * invl;
        *(float4*)(CTX + ((size_t)(b * T1C + i0 + ty * 4 + ii)) * E_ + h * DK + tx * 4) = res;
    }
}

extern "C" void kernel_launch(void* const* d_in, const int* in_sizes, int n_in,
                              void* d_out, int out_size, void* d_ws, size_t ws_size,
                              hipStream_t stream) {
    const float* query   = (const float*)d_in[0];
    const float* key     = (const float*)d_in[1];
    const float* value   = (const float*)d_in[2];
    const float* pos_enc = (const float*)d_in[3];
    const unsigned char* mask       = (const unsigned char*)d_in[4];
    const unsigned char* chunk_mask = (const unsigned char*)d_in[5];
    const float* Wq  = (const float*)d_in[6];
    const float* bq  = (const float*)d_in[7];
    const float* Wk  = (const float*)d_in[8];
    const float* bk  = (const float*)d_in[9];
    const float* Wv  = (const float*)d_in[10];
    const float* bv  = (const float*)d_in[11];
    const float* Wpos = (const float*)d_in[12];
    const float* Wo   = (const float*)d_in[13];
    const float* bo   = (const float*)d_in[14];
    const float* pbu  = (const float*)d_in[15];
    const float* pbv  = (const float*)d_in[16];
    float* out = (float*)d_out;

    float* ws = (float*)d_ws;
    const size_t SZ = (size_t)BB * T1C * E_;       // 4,194,304 floats
    float* Qo = ws;                                 // (B,T1,E); also CTX (safe alias)
    float* Kh = ws + SZ;                            // (B,H,T2,DK)
    float* Vh = ws + 2 * SZ;                        // (B,H,T2,DK)
    float* Ph = ws + 3 * SZ;                        // (B,H,NPOS,DK)

    const int Mqkv = BB * T1C;      // 8192
    const int Mpos = BB * NPOS;     // 16368

    dim3 gblk(256);
    dim3 ggrid(E_ / 64, (Mqkv + 63) / 64);
    dim3 pgrid(E_ / 64, (Mpos + 63) / 64);

    gemm_nt<<<ggrid, gblk, 0, stream>>>(query,   Wq,   bq,      Qo, Mqkv, 0);
    gemm_nt<<<ggrid, gblk, 0, stream>>>(key,     Wk,   bk,      Kh, Mqkv, 1);
    gemm_nt<<<ggrid, gblk, 0, stream>>>(value,   Wv,   bv,      Vh, Mqkv, 1);
    gemm_nt<<<pgrid, gblk, 0, stream>>>(pos_enc, Wpos, nullptr, Ph, Mpos, 2);

    dim3 agrid(T1C / 64, H_, BB);
    attn_tiled<<<agrid, dim3(256), 0, stream>>>(Qo, Kh, Vh, Ph, pbu, pbv,
                                                mask, chunk_mask, Qo /*CTX*/);

    gemm_nt<<<ggrid, gblk, 0, stream>>>(Qo, Wo, bo, out, Mqkv, 0);
}

// Round 3
// 508.649 us; speedup vs baseline: 11.5955x; 2.0235x over previous
//
#include <hip/hip_runtime.h>
#include <math.h>

typedef _Float16 f16;
typedef f16 f16x8 __attribute__((ext_vector_type(8)));
typedef f16 f16x4 __attribute__((ext_vector_type(4)));
typedef float f32x4 __attribute__((ext_vector_type(4)));

#define H_   8
#define E_   512
#define DK   64
#define BB   16
#define T1C  512
#define T2C  512
#define NPOS 1023
#define PSTR 1024   // padded positional length (t-stride in Pt)

// ---------------- cast fp32 -> fp16 (zero-pad to ndst) ----------------
struct CastDesc {
    const float* src[9];
    f16* dst[9];
    int nsrc[9];
    int ndst[9];
};
__global__ __launch_bounds__(256) void cast_f32_f16(CastDesc cd) {
    const int s = blockIdx.y;
    const float* sp = cd.src[s];
    f16* dp = cd.dst[s];
    const int n4 = cd.ndst[s] >> 2;
    const int ns = cd.nsrc[s];
    for (int i = blockIdx.x * 256 + threadIdx.x; i < n4; i += gridDim.x * 256) {
        const int base = i * 4;
        float4 v = make_float4(0.f, 0.f, 0.f, 0.f);
        if (base < ns) v = *(const float4*)(sp + base);
        f16x4 h; h[0] = (f16)v.x; h[1] = (f16)v.y; h[2] = (f16)v.z; h[3] = (f16)v.w;
        *(f16x4*)(dp + base) = h;
    }
}

// ---------------- fp16 MFMA GEMM: C = A(M,512) @ W(512,512)^T + bias ----------------
// 128x128 tile, 4 waves, BK=32. LDS rows padded to 40 halves (80B) -> conflict-free frag reads.
// mode 0: fp32 row-major (M,512)      mode 1: f16 (B,H,DK,512) transposed
// mode 2: f16 (B,H,512,DK) row-major  mode 3: f16 (B,H,DK,PSTR) transposed, m->(b,t) via /1023
struct GArg {
    const f16* A; const f16* W; const float* bias; void* C; int Mvalid; int mode;
};
struct GArg3 { GArg g[3]; };

__device__ __forceinline__ void gemm_body(const GArg g, int bx, int by) {
    __shared__ f16 Al[128 * 40];
    __shared__ f16 Wl[128 * 40];
    const int tid = threadIdx.x;
    const int lane = tid & 63, wid = tid >> 6;
    const int m0 = by * 128, n0 = bx * 128;
    const int wm0 = (wid & 1) * 64, wn0 = (wid >> 1) * 64;

    f32x4 acc[4][4];
    #pragma unroll
    for (int a = 0; a < 4; ++a)
        #pragma unroll
        for (int b = 0; b < 4; ++b)
            acc[a][b] = (f32x4){0.f, 0.f, 0.f, 0.f};

    const int row0 = tid >> 2,         kk0 = (tid & 3) * 8;
    const int row1 = (256 + tid) >> 2, kk1 = (tid & 3) * 8;

    for (int k0 = 0; k0 < 512; k0 += 32) {
        const uint4 a0 = *(const uint4*)(g.A + (size_t)(m0 + row0) * 512 + k0 + kk0);
        const uint4 a1 = *(const uint4*)(g.A + (size_t)(m0 + row1) * 512 + k0 + kk1);
        const uint4 b0 = *(const uint4*)(g.W + (size_t)(n0 + row0) * 512 + k0 + kk0);
        const uint4 b1 = *(const uint4*)(g.W + (size_t)(n0 + row1) * 512 + k0 + kk1);
        __syncthreads();
        *(uint4*)&Al[row0 * 40 + kk0] = a0;
        *(uint4*)&Al[row1 * 40 + kk1] = a1;
        *(uint4*)&Wl[row0 * 40 + kk0] = b0;
        *(uint4*)&Wl[row1 * 40 + kk1] = b1;
        __syncthreads();
        f16x8 af[4], bf[4];
        #pragma unroll
        for (int t = 0; t < 4; ++t) {
            af[t] = *(const f16x8*)&Al[(wm0 + t * 16 + (lane & 15)) * 40 + (lane >> 4) * 8];
            bf[t] = *(const f16x8*)&Wl[(wn0 + t * 16 + (lane & 15)) * 40 + (lane >> 4) * 8];
        }
        #pragma unroll
        for (int tm = 0; tm < 4; ++tm)
            #pragma unroll
            for (int tn = 0; tn < 4; ++tn)
                acc[tm][tn] = __builtin_amdgcn_mfma_f32_16x16x32_f16(af[tm], bf[tn], acc[tm][tn], 0, 0, 0);
    }

    // epilogue. C/D layout: col = lane&15, row = (lane>>4)*4 + reg (m89-verified)
    #pragma unroll
    for (int tm = 0; tm < 4; ++tm) {
        const int mb = m0 + wm0 + tm * 16 + (lane >> 4) * 4;
        #pragma unroll
        for (int tn = 0; tn < 4; ++tn) {
            const int n = n0 + wn0 + tn * 16 + (lane & 15);
            const f32x4 a = acc[tm][tn];
            const float bs = g.bias ? g.bias[n] : 0.f;
            if (g.mode == 0) {
                float* C = (float*)g.C;
                #pragma unroll
                for (int r = 0; r < 4; ++r) C[(size_t)(mb + r) * 512 + n] = a[r] + bs;
            } else if (g.mode == 1) {
                f16* C = (f16*)g.C;
                const int b = mb >> 9, t = mb & 511;
                const int hh = n >> 6, dk = n & 63;
                f16x4 h;
                #pragma unroll
                for (int r = 0; r < 4; ++r) h[r] = (f16)(a[r] + bs);
                *(f16x4*)&C[(((size_t)b * H_ + hh) * DK + dk) * 512 + t] = h;
            } else if (g.mode == 2) {
                f16* C = (f16*)g.C;
                const int b = mb >> 9, t = mb & 511;
                const int hh = n >> 6, dk = n & 63;
                #pragma unroll
                for (int r = 0; r < 4; ++r)
                    C[(((size_t)b * H_ + hh) * 512 + t + r) * DK + dk] = (f16)(a[r] + bs);
            } else {
                f16* C = (f16*)g.C;
                const int hh = n >> 6, dk = n & 63;
                #pragma unroll
                for (int r = 0; r < 4; ++r) {
                    const int m = mb + r;
                    if (m < g.Mvalid) {
                        const int b = m / NPOS, t = m - b * NPOS;
                        C[(((size_t)b * H_ + hh) * DK + dk) * PSTR + t] = (f16)a[r];
                    }
                }
            }
        }
    }
}

__global__ __launch_bounds__(256) void gemm_qkv(GArg3 a) {
    gemm_body(a.g[blockIdx.z], blockIdx.x, blockIdx.y);
}
__global__ __launch_bounds__(256) void gemm_one(GArg g) {
    gemm_body(g, blockIdx.x, blockIdx.y);
}

// ---------------- tiled online-softmax attention with rel-shift ----------------
// Block = (64-row i-tile, h, b). Inputs pre-transposed -> all staging is contiguous copies.
__global__ __launch_bounds__(256) void attn_tiled(
    const f16* __restrict__ Qt,   // (B,H,DK,T1)
    const f16* __restrict__ Kt,   // (B,H,DK,T2)
    const f16* __restrict__ Vh,   // (B,H,T2,DK)
    const f16* __restrict__ Pt,   // (B,H,DK,PSTR)
    const float* __restrict__ pbu, const float* __restrict__ pbv,
    const unsigned char* __restrict__ bmask,   // (B,T2)
    const unsigned char* __restrict__ cmask,   // (T1,T1)
    f16* __restrict__ CTX)        // (B,T1,E) fp16
{
    __shared__ float QT[64 * 64];             // [d][r] = q + pbu
    __shared__ float slotA[64 * 64];          // K [d][c] f32 | BDW f16 64x128 | Ws f32 [r][c]
    __shared__ f16 PTh[64 * 128];             // [d][nw]
    __shared__ float dpb[DK];                 // pbv - pbu

    const int tid = threadIdx.x;
    const int tx = tid & 15, ty = tid >> 4;
    const int it = blockIdx.x, h = blockIdx.y, b = blockIdx.z;
    const int i0 = it * 64;
    const int bh = b * H_ + h;

    // Q staging: contiguous uint4 loads, contiguous float4 stores (conflict-free)
    #pragma unroll
    for (int rep = 0; rep < 2; ++rep) {
        const int flat = rep * 2048 + tid * 8;
        const int d = flat >> 6, r = flat & 63;
        union { uint4 u; f16 h8[8]; } q;
        q.u = *(const uint4*)&Qt[((size_t)bh * DK + d) * 512 + i0 + r];
        const float ua = pbu[h * DK + d];
        float4 lo, hi;
        lo.x = (float)q.h8[0] + ua; lo.y = (float)q.h8[1] + ua;
        lo.z = (float)q.h8[2] + ua; lo.w = (float)q.h8[3] + ua;
        hi.x = (float)q.h8[4] + ua; hi.y = (float)q.h8[5] + ua;
        hi.z = (float)q.h8[6] + ua; hi.w = (float)q.h8[7] + ua;
        *(float4*)&QT[d * 64 + r] = lo;
        *(float4*)&QT[d * 64 + r + 4] = hi;
    }
    if (tid < DK) dpb[tid] = pbv[h * DK + tid] - pbu[h * DK + tid];

    float m_run[4], l_run[4], o[4][4];
    #pragma unroll
    for (int ii = 0; ii < 4; ++ii) {
        m_run[ii] = -__builtin_inff(); l_run[ii] = 0.f;
        #pragma unroll
        for (int dd = 0; dd < 4; ++dd) o[ii][dd] = 0.f;
    }

    for (int jt = 0; jt < 8; ++jt) {
        const int j0 = jt * 64;
        const int nbase = j0 - i0 + 448;   // in [0, 896], multiple of 64
        __syncthreads();
        // K tile: f16 -> f32, contiguous
        #pragma unroll
        for (int rep = 0; rep < 2; ++rep) {
            const int flat = rep * 2048 + tid * 8;
            const int d = flat >> 6, c = flat & 63;
            union { uint4 u; f16 h8[8]; } k;
            k.u = *(const uint4*)&Kt[((size_t)bh * DK + d) * 512 + j0 + c];
            float4 lo, hi;
            lo.x = (float)k.h8[0]; lo.y = (float)k.h8[1]; lo.z = (float)k.h8[2]; lo.w = (float)k.h8[3];
            hi.x = (float)k.h8[4]; hi.y = (float)k.h8[5]; hi.z = (float)k.h8[6]; hi.w = (float)k.h8[7];
            *(float4*)&slotA[d * 64 + c] = lo;
            *(float4*)&slotA[d * 64 + c + 4] = hi;
        }
        // P window: straight uint4 copy (nw=127 is never read by the gather -> pad junk ok)
        #pragma unroll
        for (int rep = 0; rep < 4; ++rep) {
            const int flat = rep * 2048 + tid * 8;
            const int d = flat >> 7, nw = flat & 127;
            *(uint4*)&PTh[d * 128 + nw] =
                *(const uint4*)&Pt[((size_t)bh * DK + d) * PSTR + nbase + nw];
        }
        __syncthreads();

        // fused d-loop: AC (4x4) + windowed BD (4x8) + (pbv-pbu)·p correction
        float ac[4][4] = {}, bd[4][8] = {}, vp[8] = {};
        #pragma unroll 2
        for (int d = 0; d < DK; ++d) {
            float a[4], k4[4], p[8];
            *(float4*)a = *(const float4*)&QT[d * 64 + ty * 4];
            *(float4*)k4 = *(const float4*)&slotA[d * 64 + tx * 4];
            union { uint4 u; f16 h8[8]; } pu;
            pu.u = *(const uint4*)&PTh[d * 128 + tx * 8];
            #pragma unroll
            for (int j = 0; j < 8; ++j) p[j] = (float)pu.h8[j];
            const float db = dpb[d];
            #pragma unroll
            for (int ii = 0; ii < 4; ++ii)
                #pragma unroll
                for (int jj = 0; jj < 4; ++jj)
                    ac[ii][jj] += a[ii] * k4[jj];
            #pragma unroll
            for (int ii = 0; ii < 4; ++ii)
                #pragma unroll
                for (int jj = 0; jj < 8; ++jj)
                    bd[ii][jj] += a[ii] * p[jj];
            #pragma unroll
            for (int jj = 0; jj < 8; ++jj) vp[jj] += db * p[jj];
        }
        __syncthreads();

        // BDW -> slotA as f16 64x128
        f16* BDWh = (f16*)slotA;
        #pragma unroll
        for (int ii = 0; ii < 4; ++ii) {
            f16x8 pk;
            #pragma unroll
            for (int jj = 0; jj < 8; ++jj) pk[jj] = (f16)(bd[ii][jj] + vp[jj]);
            *(f16x8*)&BDWh[(ty * 4 + ii) * 128 + tx * 8] = pk;
        }
        __syncthreads();

        // gather shifted BD, mask, online softmax update
        float w[4][4];
        #pragma unroll
        for (int ii = 0; ii < 4; ++ii) {
            const int r = ty * 4 + ii;
            float s4[4]; unsigned mk4 = 0;
            #pragma unroll
            for (int jj = 0; jj < 4; ++jj) {
                const int c = tx * 4 + jj;
                float sv = (ac[ii][jj] + (float)BDWh[r * 128 + (c - r + 63)]) * 0.125f;
                const bool mk = (cmask[(size_t)(i0 + r) * T1C + j0 + c] |
                                 bmask[(size_t)b * T2C + j0 + c]) != 0;
                if (mk) { sv = -3.402823466e38f; mk4 |= (1u << jj); }
                s4[jj] = sv;
            }
            float tmax = fmaxf(fmaxf(s4[0], s4[1]), fmaxf(s4[2], s4[3]));
            #pragma unroll
            for (int d = 1; d < 16; d <<= 1) tmax = fmaxf(tmax, __shfl_xor(tmax, d));
            const float mnew = fmaxf(m_run[ii], tmax);
            const float alpha = __expf(m_run[ii] - mnew);
            float rsum = 0.f;
            #pragma unroll
            for (int jj = 0; jj < 4; ++jj) {
                const float e = __expf(s4[jj] - mnew);
                rsum += e;                                  // denom over all j (ref semantics)
                w[ii][jj] = ((mk4 >> jj) & 1u) ? 0.f : e;   // zero masked for PV
            }
            #pragma unroll
            for (int d = 1; d < 16; d <<= 1) rsum += __shfl_xor(rsum, d);
            l_run[ii] = l_run[ii] * alpha + rsum;
            m_run[ii] = mnew;
            #pragma unroll
            for (int dd = 0; dd < 4; ++dd) o[ii][dd] *= alpha;
        }
        __syncthreads();
        // weights row-major Ws[r][c] as float4 (conflict-free store + broadcast read)
        #pragma unroll
        for (int ii = 0; ii < 4; ++ii) {
            float4 wv; wv.x = w[ii][0]; wv.y = w[ii][1]; wv.z = w[ii][2]; wv.w = w[ii][3];
            *(float4*)&slotA[(ty * 4 + ii) * 64 + tx * 4] = wv;
        }
        __syncthreads();
        // PV: V f16 from global (L2-hot), weights broadcast from LDS
        #pragma unroll 2
        for (int cc = 0; cc < 16; ++cc) {
            float wr[4][4];
            #pragma unroll
            for (int ii = 0; ii < 4; ++ii)
                *(float4*)wr[ii] = *(const float4*)&slotA[(ty * 4 + ii) * 64 + cc * 4];
            float vv[4][4];
            #pragma unroll
            for (int q = 0; q < 4; ++q) {
                const f16x4 v4 = *(const f16x4*)&Vh[((size_t)bh * T2C + j0 + cc * 4 + q) * DK + tx * 4];
                vv[q][0] = (float)v4[0]; vv[q][1] = (float)v4[1];
                vv[q][2] = (float)v4[2]; vv[q][3] = (float)v4[3];
            }
            #pragma unroll
            for (int ii = 0; ii < 4; ++ii)
                #pragma unroll
                for (int q = 0; q < 4; ++q)
                    #pragma unroll
                    for (int dd = 0; dd < 4; ++dd)
                        o[ii][dd] += wr[ii][q] * vv[q][dd];
        }
    }

    #pragma unroll
    for (int ii = 0; ii < 4; ++ii) {
        const float invl = 1.0f / l_run[ii];
        f16x4 hv;
        hv[0] = (f16)(o[ii][0] * invl); hv[1] = (f16)(o[ii][1] * invl);
        hv[2] = (f16)(o[ii][2] * invl); hv[3] = (f16)(o[ii][3] * invl);
        *(f16x4*)&CTX[((size_t)(b * T1C + i0 + ty * 4 + ii)) * E_ + h * DK + tx * 4] = hv;
    }
}

extern "C" void kernel_launch(void* const* d_in, const int* in_sizes, int n_in,
                              void* d_out, int out_size, void* d_ws, size_t ws_size,
                              hipStream_t stream) {
    const float* query   = (const float*)d_in[0];
    const float* key     = (const float*)d_in[1];
    const float* value   = (const float*)d_in[2];
    const float* pos_enc = (const float*)d_in[3];
    const unsigned char* mask       = (const unsigned char*)d_in[4];
    const unsigned char* chunk_mask = (const unsigned char*)d_in[5];
    const float* Wq  = (const float*)d_in[6];
    const float* bq  = (const float*)d_in[7];
    const float* Wk  = (const float*)d_in[8];
    const float* bk  = (const float*)d_in[9];
    const float* Wv  = (const float*)d_in[10];
    const float* bv  = (const float*)d_in[11];
    const float* Wpos = (const float*)d_in[12];
    const float* Wo   = (const float*)d_in[13];
    const float* bo   = (const float*)d_in[14];
    const float* pbu  = (const float*)d_in[15];
    const float* pbv  = (const float*)d_in[16];
    float* out = (float*)d_out;

    // workspace (halves). total ~86.5 MB
    f16* base = (f16*)d_ws;
    size_t off = 0;
    f16* qh  = base + off; off += 4194304;     // (8192,512) ; later aliased as CTX f16
    f16* kh  = base + off; off += 4194304;
    f16* vh  = base + off; off += 4194304;
    f16* ph  = base + off; off += 8388608;     // padded to 16384 rows
    f16* wqh = base + off; off += 262144;
    f16* wkh = base + off; off += 262144;
    f16* wvh = base + off; off += 262144;
    f16* wph = base + off; off += 262144;
    f16* woh = base + off; off += 262144;
    f16* Qt  = base + off; off += 4194304;     // (B,H,DK,512)
    f16* Kt  = base + off; off += 4194304;     // (B,H,DK,512)
    f16* Vt  = base + off; off += 4194304;     // (B,H,512,DK)
    f16* Pt  = base + off; off += 8388608;     // (B,H,DK,1024)

    CastDesc cd;
    cd.src[0] = query;   cd.dst[0] = qh;  cd.nsrc[0] = 4194304; cd.ndst[0] = 4194304;
    cd.src[1] = key;     cd.dst[1] = kh;  cd.nsrc[1] = 4194304; cd.ndst[1] = 4194304;
    cd.src[2] = value;   cd.dst[2] = vh;  cd.nsrc[2] = 4194304; cd.ndst[2] = 4194304;
    cd.src[3] = pos_enc; cd.dst[3] = ph;  cd.nsrc[3] = 8380416; cd.ndst[3] = 8388608;
    cd.src[4] = Wq;   cd.dst[4] = wqh; cd.nsrc[4] = 262144; cd.ndst[4] = 262144;
    cd.src[5] = Wk;   cd.dst[5] = wkh; cd.nsrc[5] = 262144; cd.ndst[5] = 262144;
    cd.src[6] = Wv;   cd.dst[6] = wvh; cd.nsrc[6] = 262144; cd.ndst[6] = 262144;
    cd.src[7] = Wpos; cd.dst[7] = wph; cd.nsrc[7] = 262144; cd.ndst[7] = 262144;
    cd.src[8] = Wo;   cd.dst[8] = woh; cd.nsrc[8] = 262144; cd.ndst[8] = 262144;
    cast_f32_f16<<<dim3(256, 9), 256, 0, stream>>>(cd);

    GArg3 g3;
    g3.g[0] = GArg{qh, wqh, bq, (void*)Qt, 8192, 1};
    g3.g[1] = GArg{kh, wkh, bk, (void*)Kt, 8192, 1};
    g3.g[2] = GArg{vh, wvh, bv, (void*)Vt, 8192, 2};
    gemm_qkv<<<dim3(4, 64, 3), 256, 0, stream>>>(g3);

    GArg gp = GArg{ph, wph, nullptr, (void*)Pt, 16368, 3};
    gemm_one<<<dim3(4, 128), 256, 0, stream>>>(gp);

    attn_tiled<<<dim3(8, 8, 16), 256, 0, stream>>>(Qt, Kt, Vt, Pt, pbu, pbv,
                                                   mask, chunk_mask, qh /*CTX*/);

    GArg go = GArg{qh, woh, bo, (void*)out, 8192, 0};
    gemm_one<<<dim3(4, 64), 256, 0, stream>>>(go);
}

// Round 4
// 333.915 us; speedup vs baseline: 17.6633x; 1.5233x over previous
//
#include <hip/hip_runtime.h>
#include <math.h>

typedef _Float16 f16;
typedef f16 f16x8 __attribute__((ext_vector_type(8)));
typedef f16 f16x4 __attribute__((ext_vector_type(4)));
typedef float f32x4 __attribute__((ext_vector_type(4)));

#define H_   8
#define E_   512
#define DK   64
#define BB   16
#define T1C  512
#define T2C  512
#define NPOS 1023

// ---------------- cast fp32 -> fp16 (zero-pad to ndst) ----------------
struct CastDesc {
    const float* src[9];
    f16* dst[9];
    int nsrc[9];
    int ndst[9];
};
__global__ __launch_bounds__(256) void cast_f32_f16(CastDesc cd) {
    const int s = blockIdx.y;
    const float* sp = cd.src[s];
    f16* dp = cd.dst[s];
    const int n4 = cd.ndst[s] >> 2;
    const int ns = cd.nsrc[s];
    for (int i = blockIdx.x * 256 + threadIdx.x; i < n4; i += gridDim.x * 256) {
        const int base = i * 4;
        float4 v = make_float4(0.f, 0.f, 0.f, 0.f);
        if (base < ns) v = *(const float4*)(sp + base);
        f16x4 h; h[0] = (f16)v.x; h[1] = (f16)v.y; h[2] = (f16)v.z; h[3] = (f16)v.w;
        *(f16x4*)(dp + base) = h;
    }
}

// ---------------- fp16 MFMA GEMM: C = A(M,512) @ W(512,512)^T + bias(+bias2) ----------------
// modes: 0 fp32 row-major (M,512) | 1 f16 (B,H,DK,512) | 2 f16 (B,H,512,DK) | 3 f16 (B,H,NPOS,DK)
struct GArg {
    const f16* A; const f16* W; const float* bias; const float* bias2;
    void* C; int Mvalid; int mode;
};
struct GArg3 { GArg g[3]; };

__device__ __forceinline__ void gemm_body(const GArg g, int bx, int by) {
    __shared__ f16 Al[128 * 40];
    __shared__ f16 Wl[128 * 40];
    const int tid = threadIdx.x;
    const int lane = tid & 63, wid = tid >> 6;
    const int m0 = by * 128, n0 = bx * 128;
    const int wm0 = (wid & 1) * 64, wn0 = (wid >> 1) * 64;

    f32x4 acc[4][4];
    #pragma unroll
    for (int a = 0; a < 4; ++a)
        #pragma unroll
        for (int b = 0; b < 4; ++b)
            acc[a][b] = (f32x4){0.f, 0.f, 0.f, 0.f};

    const int row0 = tid >> 2,         kk0 = (tid & 3) * 8;
    const int row1 = (256 + tid) >> 2, kk1 = (tid & 3) * 8;

    for (int k0 = 0; k0 < 512; k0 += 32) {
        const uint4 a0 = *(const uint4*)(g.A + (size_t)(m0 + row0) * 512 + k0 + kk0);
        const uint4 a1 = *(const uint4*)(g.A + (size_t)(m0 + row1) * 512 + k0 + kk1);
        const uint4 b0 = *(const uint4*)(g.W + (size_t)(n0 + row0) * 512 + k0 + kk0);
        const uint4 b1 = *(const uint4*)(g.W + (size_t)(n0 + row1) * 512 + k0 + kk1);
        __syncthreads();
        *(uint4*)&Al[row0 * 40 + kk0] = a0;
        *(uint4*)&Al[row1 * 40 + kk1] = a1;
        *(uint4*)&Wl[row0 * 40 + kk0] = b0;
        *(uint4*)&Wl[row1 * 40 + kk1] = b1;
        __syncthreads();
        f16x8 af[4], bf[4];
        #pragma unroll
        for (int t = 0; t < 4; ++t) {
            af[t] = *(const f16x8*)&Al[(wm0 + t * 16 + (lane & 15)) * 40 + (lane >> 4) * 8];
            bf[t] = *(const f16x8*)&Wl[(wn0 + t * 16 + (lane & 15)) * 40 + (lane >> 4) * 8];
        }
        #pragma unroll
        for (int tm = 0; tm < 4; ++tm)
            #pragma unroll
            for (int tn = 0; tn < 4; ++tn)
                acc[tm][tn] = __builtin_amdgcn_mfma_f32_16x16x32_f16(af[tm], bf[tn], acc[tm][tn], 0, 0, 0);
    }

    // C/D layout: col = lane&15, row = (lane>>4)*4 + reg
    #pragma unroll
    for (int tm = 0; tm < 4; ++tm) {
        const int mb = m0 + wm0 + tm * 16 + (lane >> 4) * 4;
        #pragma unroll
        for (int tn = 0; tn < 4; ++tn) {
            const int n = n0 + wn0 + tn * 16 + (lane & 15);
            const f32x4 a = acc[tm][tn];
            float bs = g.bias ? g.bias[n] : 0.f;
            if (g.bias2) bs += g.bias2[n];
            if (g.mode == 0) {
                float* C = (float*)g.C;
                #pragma unroll
                for (int r = 0; r < 4; ++r) C[(size_t)(mb + r) * 512 + n] = a[r] + bs;
            } else if (g.mode == 1) {
                f16* C = (f16*)g.C;
                const int b = mb >> 9, t = mb & 511;
                const int hh = n >> 6, dk = n & 63;
                f16x4 h;
                #pragma unroll
                for (int r = 0; r < 4; ++r) h[r] = (f16)(a[r] + bs);
                *(f16x4*)&C[(((size_t)b * H_ + hh) * DK + dk) * 512 + t] = h;
            } else if (g.mode == 2) {
                f16* C = (f16*)g.C;
                const int b = mb >> 9, t = mb & 511;
                const int hh = n >> 6, dk = n & 63;
                #pragma unroll
                for (int r = 0; r < 4; ++r)
                    C[(((size_t)b * H_ + hh) * 512 + t + r) * DK + dk] = (f16)(a[r] + bs);
            } else {
                f16* C = (f16*)g.C;
                const int hh = n >> 6, dk = n & 63;
                #pragma unroll
                for (int r = 0; r < 4; ++r) {
                    const int m = mb + r;
                    if (m < g.Mvalid) {
                        const int b = m / NPOS, t = m - b * NPOS;
                        C[(((size_t)b * H_ + hh) * NPOS + t) * DK + dk] = (f16)a[r];
                    }
                }
            }
        }
    }
}

__global__ __launch_bounds__(256) void gemm_qkv(GArg3 a) {
    gemm_body(a.g[blockIdx.z], blockIdx.x, blockIdx.y);
}
__global__ __launch_bounds__(256) void gemm_one(GArg g) {
    gemm_body(g, blockIdx.x, blockIdx.y);
}

// ---------------- MFMA flash attention with rel-shift ----------------
// Block = (64-row i-tile, h, b); 4 waves; wave w owns rows [w*16, w*16+16).
// LDS: Qa 9216 + Ka 9216 (reused for W) + Va 9216 + Pa 18432 (reused for BDW) = 46 KB
__global__ __launch_bounds__(256) void attn_mfma(
    const f16* __restrict__ Qh,   // (B,H,T1,DK) = q + bq + pbu
    const f16* __restrict__ Kh,   // (B,H,T2,DK)
    const f16* __restrict__ Vt,   // (B,H,DK,T2)
    const f16* __restrict__ Ph,   // (B,H,NPOS,DK)
    const float* __restrict__ pbu, const float* __restrict__ pbv,
    const unsigned char* __restrict__ bmask,   // (B,T2)
    const unsigned char* __restrict__ cmask,   // (T1,T1)
    f16* __restrict__ CTX)        // (B,T1,E) f16
{
    __shared__ f16 Qa[64 * 72];
    __shared__ f16 Ka[64 * 72];    // K tile; reused as W[r][j] after barrier D
    __shared__ f16 Va[64 * 72];    // V^T tile [d][j]
    __shared__ f16 Pa[128 * 72];   // P window [nw][d]; reused as BDW[nw][68]

    const int tid = threadIdx.x;
    const int lane = tid & 63, w = tid >> 6;
    const int quad = lane >> 4, l15 = lane & 15;
    const int it = blockIdx.x, h = blockIdx.y, b = blockIdx.z;
    const int i0 = it * 64;
    const int bh = b * H_ + h;
    const int rowt = w * 16 + quad * 4;   // this lane's tile-local row base

    // stage Q tile (contiguous copy; pbu/bq pre-folded)
    #pragma unroll
    for (int rep = 0; rep < 2; ++rep) {
        const int flat = rep * 2048 + tid * 8;
        const int r = flat >> 6, c = flat & 63;
        *(uint4*)&Qa[r * 72 + c] = *(const uint4*)&Qh[((size_t)bh * 512 + i0 + r) * 64 + c];
    }
    // dpb A-frag correction: (pbv - pbu) at k = ks*32 + quad*8 + j
    f16x8 dpbf[2];
    #pragma unroll
    for (int ks = 0; ks < 2; ++ks)
        #pragma unroll
        for (int j = 0; j < 8; ++j) {
            const int d = ks * 32 + quad * 8 + j;
            dpbf[ks][j] = (f16)(pbv[h * 64 + d] - pbu[h * 64 + d]);
        }

    float m_run[4], l_run[4];
    f32x4 accO[4];
    #pragma unroll
    for (int x = 0; x < 4; ++x) {
        m_run[x] = -__builtin_inff(); l_run[x] = 0.f;
        accO[x] = (f32x4){0.f, 0.f, 0.f, 0.f};
    }

    for (int jt = 0; jt < 8; ++jt) {
        const int j0 = jt * 64;
        const int nbase = j0 - i0 + 448;              // [0, 896]
        __syncthreads();                              // A: prev PV/gather done
        #pragma unroll
        for (int rep = 0; rep < 2; ++rep) {
            const int flat = rep * 2048 + tid * 8;
            const int r = flat >> 6, c = flat & 63;
            *(uint4*)&Ka[r * 72 + c] = *(const uint4*)&Kh[((size_t)bh * 512 + j0 + r) * 64 + c];
            *(uint4*)&Va[r * 72 + c] = *(const uint4*)&Vt[((size_t)bh * 64 + r) * 512 + j0 + c];
        }
        #pragma unroll
        for (int rep = 0; rep < 4; ++rep) {
            const int flat = rep * 2048 + tid * 8;
            const int nw = flat >> 6, c = flat & 63;
            int n = nbase + nw; n = n > (NPOS - 1) ? (NPOS - 1) : n;  // nw=127 unused
            *(uint4*)&Pa[nw * 72 + c] = *(const uint4*)&Ph[((size_t)bh * NPOS + n) * 64 + c];
        }
        __syncthreads();                              // B: staging visible

        f16x8 afQ[2], afV[2];
        #pragma unroll
        for (int ks = 0; ks < 2; ++ks) {
            afQ[ks] = *(const f16x8*)&Qa[(w * 16 + l15) * 72 + ks * 32 + quad * 8];
            afV[ks] = afQ[ks] + dpbf[ks];
        }
        f32x4 accAC[4], accBD[8];
        #pragma unroll
        for (int nt = 0; nt < 4; ++nt) {
            accAC[nt] = (f32x4){0.f, 0.f, 0.f, 0.f};
            #pragma unroll
            for (int ks = 0; ks < 2; ++ks) {
                const f16x8 bf = *(const f16x8*)&Ka[(nt * 16 + l15) * 72 + ks * 32 + quad * 8];
                accAC[nt] = __builtin_amdgcn_mfma_f32_16x16x32_f16(afQ[ks], bf, accAC[nt], 0, 0, 0);
            }
        }
        #pragma unroll
        for (int nt = 0; nt < 8; ++nt) {
            accBD[nt] = (f32x4){0.f, 0.f, 0.f, 0.f};
            #pragma unroll
            for (int ks = 0; ks < 2; ++ks) {
                const f16x8 bf = *(const f16x8*)&Pa[(nt * 16 + l15) * 72 + ks * 32 + quad * 8];
                accBD[nt] = __builtin_amdgcn_mfma_f32_16x16x32_f16(afV[ks], bf, accBD[nt], 0, 0, 0);
            }
        }
        __syncthreads();                              // C: Pa/Ka frag reads done
        // BDW[nw][68] (transposed store -> ds_write_b64), into Pa slot
        f16* BDW = Pa;
        #pragma unroll
        for (int nt = 0; nt < 8; ++nt) {
            f16x4 pk;
            #pragma unroll
            for (int rg = 0; rg < 4; ++rg) pk[rg] = (f16)accBD[nt][rg];
            *(f16x4*)&BDW[(nt * 16 + l15) * 68 + rowt] = pk;
        }
        __syncthreads();                              // D: BDW visible

        // gather + mask + online softmax; W -> Ka slot
        #pragma unroll
        for (int rg = 0; rg < 4; ++rg) {
            const int rt = rowt + rg;
            const int gi = i0 + rt;
            float sv[4]; unsigned mk = 0;
            #pragma unroll
            for (int nt = 0; nt < 4; ++nt) {
                const int c = nt * 16 + l15;
                const int nw = c - rt + 63;
                float s = (accAC[nt][rg] + (float)BDW[nw * 68 + rt]) * 0.125f;
                const bool m = (cmask[(size_t)gi * 512 + j0 + c] |
                                bmask[(size_t)b * 512 + j0 + c]) != 0;
                if (m) { s = -3.402823466e38f; mk |= 1u << nt; }
                sv[nt] = s;
            }
            float tmax = fmaxf(fmaxf(sv[0], sv[1]), fmaxf(sv[2], sv[3]));
            #pragma unroll
            for (int d = 1; d < 16; d <<= 1) tmax = fmaxf(tmax, __shfl_xor(tmax, d));
            const float mnew = fmaxf(m_run[rg], tmax);
            const float alpha = __expf(m_run[rg] - mnew);
            float rsum = 0.f;
            f16 wv[4];
            #pragma unroll
            for (int nt = 0; nt < 4; ++nt) {
                const float e = __expf(sv[nt] - mnew);
                rsum += e;                                      // denom over all j (ref)
                wv[nt] = ((mk >> nt) & 1u) ? (f16)0.f : (f16)e; // zero masked for PV
            }
            #pragma unroll
            for (int d = 1; d < 16; d <<= 1) rsum += __shfl_xor(rsum, d);
            l_run[rg] = l_run[rg] * alpha + rsum;
            m_run[rg] = mnew;
            #pragma unroll
            for (int dt = 0; dt < 4; ++dt) accO[dt][rg] *= alpha;
            #pragma unroll
            for (int nt = 0; nt < 4; ++nt)
                Ka[rt * 72 + nt * 16 + l15] = wv[nt];
        }
        __syncthreads();                              // E: W visible
        // PV: O += W @ V^T
        f16x8 afW[2];
        #pragma unroll
        for (int ks = 0; ks < 2; ++ks)
            afW[ks] = *(const f16x8*)&Ka[(w * 16 + l15) * 72 + ks * 32 + quad * 8];
        #pragma unroll
        for (int dt = 0; dt < 4; ++dt)
            #pragma unroll
            for (int ks = 0; ks < 2; ++ks) {
                const f16x8 bf = *(const f16x8*)&Va[(dt * 16 + l15) * 72 + ks * 32 + quad * 8];
                accO[dt] = __builtin_amdgcn_mfma_f32_16x16x32_f16(afW[ks], bf, accO[dt], 0, 0, 0);
            }
    }

    #pragma unroll
    for (int rg = 0; rg < 4; ++rg) {
        const float inv = 1.0f / l_run[rg];
        const int gi = i0 + rowt + rg;
        #pragma unroll
        for (int dt = 0; dt < 4; ++dt)
            CTX[((size_t)b * 512 + gi) * 512 + h * 64 + dt * 16 + l15] = (f16)(accO[dt][rg] * inv);
    }
}

extern "C" void kernel_launch(void* const* d_in, const int* in_sizes, int n_in,
                              void* d_out, int out_size, void* d_ws, size_t ws_size,
                              hipStream_t stream) {
    const float* query   = (const float*)d_in[0];
    const float* key     = (const float*)d_in[1];
    const float* value   = (const float*)d_in[2];
    const float* pos_enc = (const float*)d_in[3];
    const unsigned char* mask       = (const unsigned char*)d_in[4];
    const unsigned char* chunk_mask = (const unsigned char*)d_in[5];
    const float* Wq  = (const float*)d_in[6];
    const float* bq  = (const float*)d_in[7];
    const float* Wk  = (const float*)d_in[8];
    const float* bk  = (const float*)d_in[9];
    const float* Wv  = (const float*)d_in[10];
    const float* bv  = (const float*)d_in[11];
    const float* Wpos = (const float*)d_in[12];
    const float* Wo   = (const float*)d_in[13];
    const float* bo   = (const float*)d_in[14];
    const float* pbu  = (const float*)d_in[15];
    const float* pbv  = (const float*)d_in[16];
    float* out = (float*)d_out;

    f16* base = (f16*)d_ws;
    size_t off = 0;
    f16* qh  = base + off; off += 4194304;   // f16 query (8192,512); later CTX
    f16* kh  = base + off; off += 4194304;
    f16* vh  = base + off; off += 4194304;
    f16* ph  = base + off; off += 8388608;   // padded to 16384 rows
    f16* wqh = base + off; off += 262144;
    f16* wkh = base + off; off += 262144;
    f16* wvh = base + off; off += 262144;
    f16* wph = base + off; off += 262144;
    f16* woh = base + off; off += 262144;
    f16* Qhm = base + off; off += 4194304;   // (B,H,T1,DK)  q+bq+pbu
    f16* Khm = base + off; off += 4194304;   // (B,H,T2,DK)
    f16* Vtm = base + off; off += 4194304;   // (B,H,DK,T2)
    f16* Phm = base + off; off += 8380416;   // (B,H,NPOS,DK)

    CastDesc cd;
    cd.src[0] = query;   cd.dst[0] = qh;  cd.nsrc[0] = 4194304; cd.ndst[0] = 4194304;
    cd.src[1] = key;     cd.dst[1] = kh;  cd.nsrc[1] = 4194304; cd.ndst[1] = 4194304;
    cd.src[2] = value;   cd.dst[2] = vh;  cd.nsrc[2] = 4194304; cd.ndst[2] = 4194304;
    cd.src[3] = pos_enc; cd.dst[3] = ph;  cd.nsrc[3] = 8380416; cd.ndst[3] = 8388608;
    cd.src[4] = Wq;   cd.dst[4] = wqh; cd.nsrc[4] = 262144; cd.ndst[4] = 262144;
    cd.src[5] = Wk;   cd.dst[5] = wkh; cd.nsrc[5] = 262144; cd.ndst[5] = 262144;
    cd.src[6] = Wv;   cd.dst[6] = wvh; cd.nsrc[6] = 262144; cd.ndst[6] = 262144;
    cd.src[7] = Wpos; cd.dst[7] = wph; cd.nsrc[7] = 262144; cd.ndst[7] = 262144;
    cd.src[8] = Wo;   cd.dst[8] = woh; cd.nsrc[8] = 262144; cd.ndst[8] = 262144;
    cast_f32_f16<<<dim3(256, 9), 256, 0, stream>>>(cd);

    GArg3 g3;
    g3.g[0] = GArg{qh, wqh, bq, pbu,     (void*)Qhm, 8192, 2};
    g3.g[1] = GArg{kh, wkh, bk, nullptr, (void*)Khm, 8192, 2};
    g3.g[2] = GArg{vh, wvh, bv, nullptr, (void*)Vtm, 8192, 1};
    gemm_qkv<<<dim3(4, 64, 3), 256, 0, stream>>>(g3);

    GArg gp = GArg{ph, wph, nullptr, nullptr, (void*)Phm, 16368, 3};
    gemm_one<<<dim3(4, 128), 256, 0, stream>>>(gp);

    attn_mfma<<<dim3(8, 8, 16), 256, 0, stream>>>(Qhm, Khm, Vtm, Phm, pbu, pbv,
                                                  mask, chunk_mask, qh /*CTX*/);

    GArg go = GArg{qh, woh, bo, nullptr, (void*)out, 8192, 0};
    gemm_one<<<dim3(4, 64), 256, 0, stream>>>(go);
}